// Round 1
// 175.493 us; speedup vs baseline: 1.0101x; 1.0101x over previous
//
#include <hip/hip_runtime.h>
#include <stdint.h>

using f16 = _Float16;
typedef _Float16 f16x8 __attribute__((ext_vector_type(8)));
typedef _Float16 f16x4 __attribute__((ext_vector_type(4)));
typedef float f32x4 __attribute__((ext_vector_type(4)));

constexpr int Bn    = 32;
constexpr int Sn    = 2048;
constexpr int Fn    = 128;
constexpr int DKn   = 32;
constexpr int NHn   = 16;
constexpr int FILTn = 3;
constexpr int Mn    = Bn * Sn;

// softmax scale (1/sqrt(32)) * log2(e), folded into Wq/bq at prep time.
constexpr float QSCALE = 0.1767766952966369f * 1.4426950408889634f;

// misc layout (float)
constexpr int MISC_WOEFF = 0;
constexpr int MISC_BO    = 96;
constexpr int MISC_BQ    = 99;
constexpr int MISC_BK    = 131;
constexpr int MISC_BV    = 163;

// Async global->LDS 16B copy. LDS dest = wave-uniform base + lane*16 (m104).
#define ASYNC_COPY16(gp, lp)                                                   \
    __builtin_amdgcn_global_load_lds(                                          \
        (const __attribute__((address_space(1))) uint32_t*)(const void*)(gp),  \
        (__attribute__((address_space(3))) uint32_t*)(lp), 16, 0, 0)

// s_waitcnt imm: [3:0] vmcnt, [6:4] expcnt, [11:8] lgkmcnt
#define WAIT_VM2 __builtin_amdgcn_s_waitcnt(0xF72)  // vmcnt<=2
#define WAIT_VM0 __builtin_amdgcn_s_waitcnt(0xF70)  // vmcnt<=0

// ---------------------------------------------------------------------------
// Prep kernel: pack W^T into MFMA B-fragment order (f16, scaled) + misc.
// ---------------------------------------------------------------------------
__global__ __launch_bounds__(256) void prep_kernel(
    const float* __restrict__ Wq, const float* __restrict__ bq,
    const float* __restrict__ Wk, const float* __restrict__ bk,
    const float* __restrict__ Wv, const float* __restrict__ bv,
    const float* __restrict__ Wo, const float* __restrict__ bo,
    f16* __restrict__ wtg, float* __restrict__ misc)
{
    for (int idx = blockIdx.x * 256 + threadIdx.x; idx < 3 * 4096;
         idx += gridDim.x * 256) {
        const int T    = idx >> 12;
        const int r    = idx & 4095;
        const int nt   = r >> 11;
        const int ks   = (r >> 9) & 3;
        const int lane = (r >> 3) & 63;
        const int j    = r & 7;
        const int k    = ks * 32 + (lane >> 4) * 8 + j;
        const int c    = nt * 16 + (lane & 15);
        const float* W = (T == 0) ? Wq : ((T == 1) ? Wk : Wv);
        const float sc = (T == 0) ? QSCALE : 1.0f;
        wtg[idx] = (f16)(W[k * DKn + c] * sc);
    }
    if (blockIdx.x == 0) {
        const int t = threadIdx.x;
        if (t < 96) {
            const int d = t / 3, f = t - 3 * d;
            float s = 0.f;
#pragma unroll
            for (int h = 0; h < NHn; ++h) s += Wo[(h * DKn + d) * FILTn + f];
            misc[MISC_WOEFF + t] = s;
        } else if (t < 99) {
            misc[MISC_BO + (t - 96)] = bo[t - 96];
        } else if (t < 131) {
            misc[MISC_BQ + (t - 99)] = bq[t - 99] * QSCALE;
        } else if (t < 163) {
            misc[MISC_BK + (t - 131)] = bk[t - 131];
        } else if (t < 195) {
            misc[MISC_BV + (t - 163)] = bv[t - 163];
        }
    }
}

// ---------------------------------------------------------------------------
// Kernel A: QKV projection (unchanged — evidence says proj is near its
// 100 MB-read memory floor). 2 row-groups per wave; V computed transposed.
// ---------------------------------------------------------------------------
__global__ __launch_bounds__(256) void qkv_proj(
    const float* __restrict__ q_in, const float* __restrict__ k_in,
    const float* __restrict__ v_in,
    const f16* __restrict__ wtg, const float* __restrict__ misc,
    f16* __restrict__ q_ws, f16* __restrict__ k_ws, f16* __restrict__ v_ws)
{
    const int t    = threadIdx.x;
    const int w    = t >> 6;
    const int lane = t & 63;
    const int n    = lane & 15;
    const int quad = lane >> 4;
    const int T    = blockIdx.x / 512;
    const int rowA = (((blockIdx.x - T * 512) * 4 + w)) * 32;
    const int rowB = rowA + 16;
    const float* in = (T == 0) ? q_in : ((T == 1) ? k_in : v_in);

    f16x8 wf[2][4];
#pragma unroll
    for (int nt = 0; nt < 2; ++nt)
#pragma unroll
        for (int ks = 0; ks < 4; ++ks)
            wf[nt][ks] =
                *(const f16x8*)(wtg + T * 4096 + (nt * 4 + ks) * 512 + lane * 8);

    f16x8 afA[4], afB[4];
#pragma unroll
    for (int ks = 0; ks < 4; ++ks) {
        const float* pA = in + (size_t)(rowA + n) * Fn + ks * 32 + quad * 8;
        const float* pB = in + (size_t)(rowB + n) * Fn + ks * 32 + quad * 8;
        const float4 a0 = *(const float4*)pA;
        const float4 a1 = *(const float4*)(pA + 4);
        const float4 b0 = *(const float4*)pB;
        const float4 b1 = *(const float4*)(pB + 4);
        f16x8 a, b;
        a[0]=(f16)a0.x; a[1]=(f16)a0.y; a[2]=(f16)a0.z; a[3]=(f16)a0.w;
        a[4]=(f16)a1.x; a[5]=(f16)a1.y; a[6]=(f16)a1.z; a[7]=(f16)a1.w;
        b[0]=(f16)b0.x; b[1]=(f16)b0.y; b[2]=(f16)b0.z; b[3]=(f16)b0.w;
        b[4]=(f16)b1.x; b[5]=(f16)b1.y; b[6]=(f16)b1.z; b[7]=(f16)b1.w;
        afA[ks] = a;
        afB[ks] = b;
    }

    if (T < 2) {
        const float* bb = misc + (T == 0 ? MISC_BQ : MISC_BK);
        const float b0 = bb[n], b1 = bb[16 + n];
        f32x4 accA0 = {b0, b0, b0, b0}, accA1 = {b1, b1, b1, b1};
        f32x4 accB0 = {b0, b0, b0, b0}, accB1 = {b1, b1, b1, b1};
#pragma unroll
        for (int ks = 0; ks < 4; ++ks) {
            accA0 = __builtin_amdgcn_mfma_f32_16x16x32_f16(afA[ks], wf[0][ks], accA0, 0, 0, 0);
            accA1 = __builtin_amdgcn_mfma_f32_16x16x32_f16(afA[ks], wf[1][ks], accA1, 0, 0, 0);
            accB0 = __builtin_amdgcn_mfma_f32_16x16x32_f16(afB[ks], wf[0][ks], accB0, 0, 0, 0);
            accB1 = __builtin_amdgcn_mfma_f32_16x16x32_f16(afB[ks], wf[1][ks], accB1, 0, 0, 0);
        }
        f16* ows = (T == 0) ? q_ws : k_ws;
#pragma unroll
        for (int r = 0; r < 4; ++r) {
            const int ra = rowA + quad * 4 + r;
            const int rb = rowB + quad * 4 + r;
            ows[(size_t)ra * DKn + n]      = (f16)accA0[r];
            ows[(size_t)ra * DKn + 16 + n] = (f16)accA1[r];
            ows[(size_t)rb * DKn + n]      = (f16)accB0[r];
            ows[(size_t)rb * DKn + 16 + n] = (f16)accB1[r];
        }
    } else {
        f32x4 accA0 = {0.f,0.f,0.f,0.f}, accA1 = {0.f,0.f,0.f,0.f};
        f32x4 accB0 = {0.f,0.f,0.f,0.f}, accB1 = {0.f,0.f,0.f,0.f};
#pragma unroll
        for (int ks = 0; ks < 4; ++ks) {
            accA0 = __builtin_amdgcn_mfma_f32_16x16x32_f16(wf[0][ks], afA[ks], accA0, 0, 0, 0);
            accA1 = __builtin_amdgcn_mfma_f32_16x16x32_f16(wf[1][ks], afA[ks], accA1, 0, 0, 0);
            accB0 = __builtin_amdgcn_mfma_f32_16x16x32_f16(wf[0][ks], afB[ks], accB0, 0, 0, 0);
            accB1 = __builtin_amdgcn_mfma_f32_16x16x32_f16(wf[1][ks], afB[ks], accB1, 0, 0, 0);
        }
        const int b  = rowA >> 11;
        const int sA = (rowA & (Sn - 1)) + n;
        const int sB = sA + 16;
#pragma unroll
        for (int r = 0; r < 4; ++r) {
            const int d0 = quad * 4 + r;
            v_ws[((size_t)(b * DKn + d0)) * Sn + sA] =
                (f16)(accA0[r] + misc[MISC_BV + d0]);
            v_ws[((size_t)(b * DKn + 16 + d0)) * Sn + sA] =
                (f16)(accA1[r] + misc[MISC_BV + 16 + d0]);
            v_ws[((size_t)(b * DKn + d0)) * Sn + sB] =
                (f16)(accB0[r] + misc[MISC_BV + d0]);
            v_ws[((size_t)(b * DKn + 16 + d0)) * Sn + sB] =
                (f16)(accB1[r] + misc[MISC_BV + 16 + d0]);
        }
    }
}

// ---------------------------------------------------------------------------
// Kernel B: flash attention + fused output projection — transpose-free PV.
//
// R7 change: 32 q-rows per wave (two Q fragments qa0/qa1) instead of 16.
// Each K fragment (kb) and V fragment (vb) read from LDS now feeds TWO
// QK^T / PV MFMAs — LDS read traffic per unit of work halves (was the
// dominant per-work cost: every wave reads the full 4KB K tile + 4KB of V
// fragments per kt). Block = 4 waves x 32 q = 128 q rows; grid = 512
// (2 blocks/CU, 8 waves/CU). Numerics bit-identical to R6 (same exp2,
// same RTN f16 casts, same MFMA shapes and accumulation order).
// ---------------------------------------------------------------------------
__global__ __launch_bounds__(256, 2) void flash_mfma(
    const f16* __restrict__ q_ws, const f16* __restrict__ k_ws,
    const f16* __restrict__ v_ws,
    const float* __restrict__ misc, float* __restrict__ out)
{
    __shared__ f16 kv[3][2][2048];     // [buf][K/V][4 KB tile] = 24 KB

    const int t    = threadIdx.x;
    const int w    = t >> 6;
    const int lane = t & 63;
    const int n    = lane & 15;
    const int quad = lane >> 4;
    // grid = 512: bid = y*128 + qt*8 + x; b = x*4+y keeps one batch's 16
    // q-blocks on one XCD (K/V tile L2 locality).
    const int b    = (blockIdx.x & 7) * 4 + (blockIdx.x >> 7);
    const int qt   = (blockIdx.x >> 3) & 15;

    // Swizzled per-lane DMA source offsets (f16 units, tile-relative). R6.
    const f16* Ksrc = k_ws + (size_t)b * Sn * DKn
                    + (size_t)(t >> 2) * DKn + (((t & 3) ^ ((t >> 3) & 3)) * 8);
    const f16* Vsrc = v_ws + (size_t)b * DKn * Sn
                    + (size_t)(t >> 3) * Sn + (((t & 7) ^ ((t >> 3) & 7)) * 8);

#define STAGE(KT, BUF)                                              \
    {                                                               \
        ASYNC_COPY16(Ksrc + (size_t)(KT) * 2048, &kv[BUF][0][w * 512]); \
        ASYNC_COPY16(Vsrc + (size_t)(KT) * 64,   &kv[BUF][1][w * 512]); \
    }

    // Two q-row groups per wave: rows qrow0+qg*16+{n}, qg in {0,1}.
    const int qrow0 = b * Sn + qt * 128 + w * 32;
    const f16x8 qa0 = *(const f16x8*)(q_ws + (size_t)(qrow0 + n) * DKn + quad * 8);
    const f16x8 qa1 = *(const f16x8*)(q_ws + (size_t)(qrow0 + 16 + n) * DKn + quad * 8);

    // K fragment offsets (R6, measured 0 conflicts).
    int koff[4];
#pragma unroll
    for (int g = 0; g < 4; ++g)
        koff[g] = (g * 64 + n * 4 + (quad ^ ((n >> 1) & 3))) * 8;

    // V b64 fragment offsets: element V^T[d][key], d=h*16+n,
    // key = s*16 + quad*4 + j. Image chunk (d,jc=key>>3) at pos d*8+(jc^(d&7)).
    int voff2[2][4];
#pragma unroll
    for (int h = 0; h < 2; ++h)
#pragma unroll
        for (int s = 0; s < 4; ++s) {
            const int d  = h * 16 + n;
            const int jc = s * 2 + (quad >> 1);
            voff2[h][s] = (d * 8 + (jc ^ (d & 7))) * 8 + (quad & 1) * 4;
        }

    f32x4 o00 = {0.f, 0.f, 0.f, 0.f};   // qg0, d 0..15
    f32x4 o01 = {0.f, 0.f, 0.f, 0.f};   // qg0, d 16..31
    f32x4 o10 = {0.f, 0.f, 0.f, 0.f};   // qg1, d 0..15
    f32x4 o11 = {0.f, 0.f, 0.f, 0.f};   // qg1, d 16..31
    float l0 = 0.f, l1 = 0.f;
    const f32x4 zero = {0.f, 0.f, 0.f, 0.f};

    STAGE(0, 0)
    STAGE(1, 1)

#pragma unroll 1
    for (int kt = 0; kt < Sn / 64; ++kt) {
        const int cur = kt % 3;
        WAIT_VM2;                          // this wave's tile-kt DMAs done
        __builtin_amdgcn_s_barrier();      // all 4 waves' quarters visible
        STAGE((kt + 2) & 31, (kt + 2) % 3) // prefetch distance 2

        const f16* Kt = &kv[cur][0][0];
        const f16* Vt = &kv[cur][1][0];

        const f16x8 kb0 = *(const f16x8*)(Kt + koff[0]);
        const f16x8 kb1 = *(const f16x8*)(Kt + koff[1]);
        const f16x8 kb2 = *(const f16x8*)(Kt + koff[2]);
        const f16x8 kb3 = *(const f16x8*)(Kt + koff[3]);
        f16x4 vb[2][4];
#pragma unroll
        for (int h = 0; h < 2; ++h)
#pragma unroll
            for (int s = 0; s < 4; ++s)
                vb[h][s] = *(const f16x4*)(Vt + voff2[h][s]);

        // S^T per q-group: lane(n,quad) reg r = S[q=n][key = g*16+quad*4+r].
        // Each kb feeds BOTH q-groups (the LDS-traffic halving).
        f16x4 pa0[4], pa1[4];
#define QK_GROUP(g, kbg)                                                       \
        {                                                                      \
            const f32x4 sa =                                                   \
                __builtin_amdgcn_mfma_f32_16x16x32_f16(kbg, qa0, zero, 0, 0, 0);\
            const f32x4 sb =                                                   \
                __builtin_amdgcn_mfma_f32_16x16x32_f16(kbg, qa1, zero, 0, 0, 0);\
            const float a0 = __builtin_amdgcn_exp2f(sa[0]);                    \
            const float a1 = __builtin_amdgcn_exp2f(sa[1]);                    \
            const float a2 = __builtin_amdgcn_exp2f(sa[2]);                    \
            const float a3 = __builtin_amdgcn_exp2f(sa[3]);                    \
            l0 += (a0 + a1) + (a2 + a3);                                       \
            f16x4 ppa;                                                         \
            ppa[0] = (f16)a0; ppa[1] = (f16)a1;                                \
            ppa[2] = (f16)a2; ppa[3] = (f16)a3;                                \
            pa0[g] = ppa;                                                      \
            const float b0 = __builtin_amdgcn_exp2f(sb[0]);                    \
            const float b1 = __builtin_amdgcn_exp2f(sb[1]);                    \
            const float b2 = __builtin_amdgcn_exp2f(sb[2]);                    \
            const float b3 = __builtin_amdgcn_exp2f(sb[3]);                    \
            l1 += (b0 + b1) + (b2 + b3);                                       \
            f16x4 ppb;                                                         \
            ppb[0] = (f16)b0; ppb[1] = (f16)b1;                                \
            ppb[2] = (f16)b2; ppb[3] = (f16)b3;                                \
            pa1[g] = ppb;                                                      \
        }
        QK_GROUP(0, kb0)
        QK_GROUP(1, kb1)
        QK_GROUP(2, kb2)
        QK_GROUP(3, kb3)
#undef QK_GROUP

        // PV: A = P (direct from registers), B = V^T frags. K=16 per step.
        // Each vb feeds BOTH q-groups.
#pragma unroll
        for (int s = 0; s < 4; ++s) {
            o00 = __builtin_amdgcn_mfma_f32_16x16x16f16(pa0[s], vb[0][s], o00, 0, 0, 0);
            o01 = __builtin_amdgcn_mfma_f32_16x16x16f16(pa0[s], vb[1][s], o01, 0, 0, 0);
            o10 = __builtin_amdgcn_mfma_f32_16x16x16f16(pa1[s], vb[0][s], o10, 0, 0, 0);
            o11 = __builtin_amdgcn_mfma_f32_16x16x16f16(pa1[s], vb[1][s], o11, 0, 0, 0);
        }
    }
#undef STAGE
    WAIT_VM0;   // drain tail prefetches before exit

    // l: per-lane partial covers q=n (within its q-group); sum across quads.
    l0 += __shfl_xor(l0, 16);
    l0 += __shfl_xor(l0, 32);   // every lane: l[qg0, q=n]
    l1 += __shfl_xor(l1, 16);
    l1 += __shfl_xor(l1, 32);   // every lane: l[qg1, q=n]

    // epilogue: out[row][f] = sum_d (O[row][d]/l) * Wo_eff[d][f] + bo[f]
    float w0f[FILTn], w1f[FILTn];
#pragma unroll
    for (int f = 0; f < FILTn; ++f) {
        w0f[f] = misc[MISC_WOEFF + n * FILTn + f];
        w1f[f] = misc[MISC_WOEFF + (16 + n) * FILTn + f];
    }
#pragma unroll
    for (int qg = 0; qg < 2; ++qg) {
        const float lf = (qg == 0) ? l0 : l1;
        const f32x4 oA = (qg == 0) ? o00 : o10;
        const f32x4 oB = (qg == 0) ? o01 : o11;
#pragma unroll
        for (int r = 0; r < 4; ++r) {
            const float inv = 1.f / __shfl(lf, quad * 4 + r);  // l for q=quad*4+r
            const float a0 = oA[r] * inv;
            const float a1 = oB[r] * inv;
#pragma unroll
            for (int f = 0; f < FILTn; ++f) {
                float v = a0 * w0f[f] + a1 * w1f[f];
                v += __shfl_xor(v, 1, 16);
                v += __shfl_xor(v, 2, 16);
                v += __shfl_xor(v, 4, 16);
                v += __shfl_xor(v, 8, 16);
                if (n == f) {
                    const int row = qrow0 + qg * 16 + quad * 4 + r;
                    out[(size_t)row * FILTn + f] = v + misc[MISC_BO + f];
                }
            }
        }
    }
}

// ---------------------------------------------------------------------------
// Launch. ws layout (f16): q_ws | k_ws | v_ws (4 MiB each), wtg, misc.
// ---------------------------------------------------------------------------
extern "C" void kernel_launch(void* const* d_in, const int* in_sizes, int n_in,
                              void* d_out, int out_size, void* d_ws,
                              size_t ws_size, hipStream_t stream)
{
    const float* q_in = (const float*)d_in[0];
    const float* k_in = (const float*)d_in[1];
    const float* v_in = (const float*)d_in[2];
    const float* Wq   = (const float*)d_in[3];
    const float* bq   = (const float*)d_in[4];
    const float* Wk   = (const float*)d_in[5];
    const float* bk   = (const float*)d_in[6];
    const float* Wv   = (const float*)d_in[7];
    const float* bv   = (const float*)d_in[8];
    const float* Wo   = (const float*)d_in[9];
    const float* bo   = (const float*)d_in[10];
    float* out = (float*)d_out;

    f16*   ws   = (f16*)d_ws;
    f16*   q_ws = ws;
    f16*   k_ws = ws + (size_t)Mn * DKn;
    f16*   v_ws = ws + 2 * (size_t)Mn * DKn;
    f16*   wtg  = ws + 3 * (size_t)Mn * DKn;
    float* misc = (float*)(wtg + 3 * 4096);

    prep_kernel<<<16, 256, 0, stream>>>(Wq, bq, Wk, bk, Wv, bv, Wo, bo, wtg, misc);

    qkv_proj<<<3 * 512, 256, 0, stream>>>(
        q_in, k_in, v_in, wtg, misc, q_ws, k_ws, v_ws);

    flash_mfma<<<Bn * (Sn / 128), 256, 0, stream>>>(
        q_ws, k_ws, v_ws, misc, out);
}